// Round 17
// baseline (857.732 us; speedup 1.0000x reference)
//
#include <hip/hip_runtime.h>
#include <cstddef>
#include <cstdint>

static constexpr int Bc   = 4;
static constexpr int Lq   = 4096;
static constexpr int Dm   = 1024;
static constexpr int Dmlp = 4096;
static constexpr int Mrows = Bc * Lq;   // 16384
static constexpr int Lk1   = Lq + 1;    // 4097

typedef unsigned short u16;
typedef __bf16 bf16_t;
typedef bf16_t bf16x8 __attribute__((ext_vector_type(8)));
typedef float  f32x4  __attribute__((ext_vector_type(4)));
typedef float  f32x16 __attribute__((ext_vector_type(16)));

__device__ __forceinline__ u16 f2b(float f) {
    uint32_t u = __builtin_bit_cast(uint32_t, f);
    return (u16)((u + 0x7FFFu + ((u >> 16) & 1u)) >> 16);
}
__device__ __forceinline__ float b2f(u16 h) {
    uint32_t u = ((uint32_t)h) << 16;
    return __builtin_bit_cast(float, u);
}

#define GLL16(gsrc, ldst) \
    __builtin_amdgcn_global_load_lds( \
        (const __attribute__((address_space(1))) void*)(gsrc), \
        (__attribute__((address_space(3))) void*)(ldst), 16, 0, 0)

// ---------------------------------------------------------------------------
// 64x64 transpose+convert tile (device helper)
// ---------------------------------------------------------------------------
__device__ __forceinline__
void transpose_tile(const float* __restrict__ in, u16* __restrict__ outp,
                    int R, int C, int tx, int ty) {
    __shared__ float tile[64][65];
    const int r0 = ty * 64, c0 = tx * 64;
    const int t = threadIdx.x;
    const int lr = t >> 2, lc0 = (t & 3) * 16;
    #pragma unroll
    for (int j = 0; j < 4; ++j) {
        float4 v = *(const float4*)&in[(size_t)(r0 + lr) * C + c0 + lc0 + j * 4];
        tile[lr][lc0 + j * 4 + 0] = v.x;
        tile[lr][lc0 + j * 4 + 1] = v.y;
        tile[lr][lc0 + j * 4 + 2] = v.z;
        tile[lr][lc0 + j * 4 + 3] = v.w;
    }
    __syncthreads();
    const int oc = t >> 2, rr0 = (t & 3) * 16;
    union { u16 u[16]; uint4 v[2]; } pk;
    #pragma unroll
    for (int j = 0; j < 16; ++j) pk.u[j] = f2b(tile[rr0 + j][oc]);
    u16* po = &outp[(size_t)(c0 + oc) * R + r0 + rr0];
    *(uint4*)&po[0] = pk.v[0];
    *(uint4*)&po[8] = pk.v[1];
}

// ---------------------------------------------------------------------------
// prep: cvt x->bf16 | 7 weight transposes | zero qp/KV/Ksum | bias concat
// ---------------------------------------------------------------------------
__global__ __launch_bounds__(256)
void prep_kernel(const float* __restrict__ x, u16* __restrict__ xb,
                 const float* __restrict__ Wq, const float* __restrict__ Wk,
                 const float* __restrict__ Wv, const float* __restrict__ Wfq,
                 const float* __restrict__ Wfk, const float* __restrict__ W1,
                 const float* __restrict__ W2,
                 u16* __restrict__ Wtq, u16* __restrict__ Wtk,
                 u16* __restrict__ Wtv, u16* __restrict__ Wtfq,
                 u16* __restrict__ Wtfk, u16* __restrict__ Wt1,
                 u16* __restrict__ Wt2,
                 const float* __restrict__ bq, const float* __restrict__ bk,
                 float* __restrict__ bqk,
                 float* __restrict__ zp, int nz) {
    int bid = blockIdx.x;
    if (bid < 2048) {
        const int n = Mrows * Dm;
        for (int i = (bid * 256 + threadIdx.x) * 4; i < n; i += 2048 * 256 * 4) {
            float4 v = *(const float4*)&x[i];
            ushort4 o = { f2b(v.x), f2b(v.y), f2b(v.z), f2b(v.w) };
            *(ushort4*)&xb[i] = o;
        }
        return;
    }
    bid -= 2048;
    if (bid < 3328) {
        const float* src; u16* dst; int R, C, tx, ty;
        if (bid < 1280) {
            const int wsel = bid >> 8, rem = bid & 255;
            if      (wsel == 0) { src = Wq;  dst = Wtq;  }
            else if (wsel == 1) { src = Wk;  dst = Wtk;  }
            else if (wsel == 2) { src = Wv;  dst = Wtv;  }
            else if (wsel == 3) { src = Wfq; dst = Wtfq; }
            else                { src = Wfk; dst = Wtfk; }
            R = 1024; C = 1024; tx = rem & 15; ty = rem >> 4;
        } else if (bid < 2304) {
            const int rem = bid - 1280;
            src = W1; dst = Wt1; R = 1024; C = 4096; tx = rem & 63; ty = rem >> 6;
        } else {
            const int rem = bid - 2304;
            src = W2; dst = Wt2; R = 4096; C = 1024; tx = rem & 15; ty = rem >> 4;
        }
        transpose_tile(src, dst, R, C, tx, ty);
        return;
    }
    bid -= 3328;
    if (bid < 1056) {
        const int i = bid * 256 + threadIdx.x;
        if (i < nz) zp[i] = 0.0f;
        return;
    }
    bid -= 1056;
    const int i = bid * 256 + threadIdx.x;
    bqk[i] = (i < 1024) ? bq[i] : bk[i - 1024];
}

// ---------------------------------------------------------------------------
// KVT[bh][e][d] = bf16(KV[bh][d][e])
// ---------------------------------------------------------------------------
__global__ __launch_bounds__(256)
void kvt_cvt_kernel(const float* __restrict__ KV, u16* __restrict__ KVT) {
    const int bh = blockIdx.x;
    __shared__ float t[64][65];
    const int tid = threadIdx.x;
    const int r = tid >> 2, c0 = (tid & 3) * 16;
    const float* src = &KV[(size_t)bh * 4096];
    #pragma unroll
    for (int j = 0; j < 4; ++j) {
        float4 v = *(const float4*)&src[r * 64 + c0 + j * 4];
        t[r][c0 + j * 4 + 0] = v.x;
        t[r][c0 + j * 4 + 1] = v.y;
        t[r][c0 + j * 4 + 2] = v.z;
        t[r][c0 + j * 4 + 3] = v.w;
    }
    __syncthreads();
    const int e = tid >> 2, d0 = (tid & 3) * 16;
    union { u16 u[16]; uint4 v[2]; } pk;
    #pragma unroll
    for (int j = 0; j < 16; ++j) pk.u[j] = f2b(t[d0 + j][e]);
    u16* po = &KVT[(size_t)bh * 4096 + e * 64 + d0];
    *(uint4*)&po[0] = pk.v[0];
    *(uint4*)&po[8] = pk.v[1];
}

// ---------------------------------------------------------------------------
// 256x256 MFMA GEMM, ring-4 schedule (r6 verbatim), 32x32x16 MFMA with
// FRAGMENT-MAJOR LDS layout (no swizzle): slot = [G=row/32][s=kslot][l31][8],
// so each wave fragment read is 1024 contiguous bytes (conflict-free floor).
// Staging realizes the layout by permuting the GLOBAL source address only
// (gload_lds dest stays linear): thread t, issue j <-> (G=t>>7+4j,
// s=(t>>5)&3, l31=t&31) <-> global row 32G+l31, k-offset 8s. Bijective.
// A/B frag: row/col = l&31, k = l5*8+j (verified: r16 passed correctness).
// C/D: col=l&31, row=(q&3)+8*(q>>2)+4*l5 [m74/m101-verified].
// ---------------------------------------------------------------------------
template<int ACT, bool RES, bool ACCUM, bool BIAS, bool OBF16>
__global__ __launch_bounds__(512, 1)
void mfma_gemm256(const u16* __restrict__ A, int ldA,
                  const u16* __restrict__ Bt, int ldB,
                  const float* __restrict__ bias,
                  void* __restrict__ Cout, void* __restrict__ Cout2,
                  int nSplit, int ldc,
                  const u16* __restrict__ res1, const float* __restrict__ res2,
                  int M, int N, int K) {
    __shared__ u16 ldsA[4][8192];
    __shared__ u16 ldsB[4][8192];
    const int tid = threadIdx.x;
    const int l   = tid & 63;
    const int w   = tid >> 6;
    const int wm  = w >> 2;
    const int wn  = w & 3;
    const int l31 = l & 31, l5 = l >> 5;

    const int gx = N >> 8;
    int bid = blockIdx.x;
    bid = (bid & 7) * ((int)gridDim.x >> 3) + (bid >> 3);
    const int brow = (bid / gx) << 8;
    const int bcol = (bid % gx) << 8;

    // staging: fragment-major content via permuted global source
    const int srow = ((tid >> 7) << 5) + (tid & 31);   // + j*128
    const int skof = ((tid >> 5) & 3) << 3;
    const u16* gA = A  + (size_t)(brow + srow) * ldA + skof;
    const u16* gB = Bt + (size_t)(bcol + srow) * ldB + skof;
    const size_t gsA = (size_t)128 * ldA;
    const size_t gsB = (size_t)128 * ldB;
    const int ldst = tid * 8;

    // fragment read offsets (contiguous per wave): base + mt*1024 + kk*512
    const int fB = l5 * 256 + l31 * 8;
    const int aBase = wm * 4096 + fB;
    const int bBase = wn * 2048 + fB;

    f32x16 acc[4][2];
    #pragma unroll
    for (int mt = 0; mt < 4; ++mt)
        #pragma unroll
        for (int nt = 0; nt < 2; ++nt)
            #pragma unroll
            for (int q = 0; q < 16; ++q) acc[mt][nt][q] = 0.f;

    auto stageA = [&](int slot, int kelem) {
        const u16* s = gA + (size_t)kelem;
        GLL16(s,       &ldsA[slot][ldst]);
        GLL16(s + gsA, &ldsA[slot][ldst + 4096]);
    };
    auto stageB = [&](int slot, int kelem) {
        const u16* s = gB + (size_t)kelem;
        GLL16(s,       &ldsB[slot][ldst]);
        GLL16(s + gsB, &ldsB[slot][ldst + 4096]);
    };

    const int T = K >> 5;
    stageA(0, 0);  stageB(0, 0);
    stageA(1, 32); stageB(1, 32);
    stageA(2, 64); stageB(2, 64);

    auto step = [&](int t, int waitsel, bool do_stage) {
        asm volatile("s_waitcnt lgkmcnt(0)" ::: "memory");
        if (waitsel == 0)      asm volatile("s_waitcnt vmcnt(8)" ::: "memory");
        else if (waitsel == 1) asm volatile("s_waitcnt vmcnt(4)" ::: "memory");
        else                   asm volatile("s_waitcnt vmcnt(0)" ::: "memory");
        asm volatile("s_barrier" ::: "memory");
        const int slot = t & 3;
        bf16x8 bfr[2][2], afr[2][2];
        #pragma unroll
        for (int nt = 0; nt < 2; ++nt)
            #pragma unroll
            for (int kk = 0; kk < 2; ++kk)
                bfr[nt][kk] = *(const bf16x8*)&ldsB[slot][bBase + nt * 1024 + kk * 512];
        #pragma unroll
        for (int mt = 0; mt < 2; ++mt)
            #pragma unroll
            for (int kk = 0; kk < 2; ++kk)
                afr[mt][kk] = *(const bf16x8*)&ldsA[slot][aBase + mt * 1024 + kk * 512];
        if (do_stage) stageA((t + 3) & 3, (t + 3) * 32);
        __builtin_amdgcn_s_setprio(1);
        #pragma unroll
        for (int mt = 0; mt < 2; ++mt)
            #pragma unroll
            for (int nt = 0; nt < 2; ++nt)
                #pragma unroll
                for (int kk = 0; kk < 2; ++kk)
                    acc[mt][nt] = __builtin_amdgcn_mfma_f32_32x32x16_bf16(
                        afr[mt][kk], bfr[nt][kk], acc[mt][nt], 0, 0, 0);
        __builtin_amdgcn_s_setprio(0);
        #pragma unroll
        for (int mt = 0; mt < 2; ++mt)
            #pragma unroll
            for (int kk = 0; kk < 2; ++kk)
                afr[mt][kk] = *(const bf16x8*)&ldsA[slot][aBase + (mt + 2) * 1024 + kk * 512];
        if (do_stage) stageB((t + 3) & 3, (t + 3) * 32);
        __builtin_amdgcn_s_setprio(1);
        #pragma unroll
        for (int mt = 0; mt < 2; ++mt)
            #pragma unroll
            for (int nt = 0; nt < 2; ++nt)
                #pragma unroll
                for (int kk = 0; kk < 2; ++kk)
                    acc[mt + 2][nt] = __builtin_amdgcn_mfma_f32_32x32x16_bf16(
                        afr[mt][kk], bfr[nt][kk], acc[mt + 2][nt], 0, 0, 0);
        __builtin_amdgcn_s_setprio(0);
    };

    for (int t = 0; t < T - 2; ++t) step(t, 0, (t + 3) < T);
    step(T - 2, 1, false);
    step(T - 1, 2, false);

    // --- epilogue (32x32 C/D layout; optional bf16 N-split) ---
    const bool hiC = (bcol >= nSplit);
    u16*   Co16 = (u16*)(hiC ? Cout2 : Cout);
    float* Co32 = (float*)Cout;
    const int bcolE = bcol - (hiC ? nSplit : 0);
    float bvn[2];
    int colE[2];
    #pragma unroll
    for (int nt = 0; nt < 2; ++nt) {
        const int cg = bcol + wn * 64 + nt * 32 + l31;
        colE[nt] = bcolE + wn * 64 + nt * 32 + l31;
        bvn[nt] = BIAS ? bias[cg] : 0.f;
    }
    #pragma unroll
    for (int mt = 0; mt < 4; ++mt) {
        #pragma unroll
        for (int q = 0; q < 16; ++q) {
            const size_t row = (size_t)brow + wm * 128 + mt * 32
                             + (q & 3) + 8 * (q >> 2) + 4 * l5;
            #pragma unroll
            for (int nt = 0; nt < 2; ++nt) {
                float v = acc[mt][nt][q] + bvn[nt];
                if (ACT == 1) v = tanhf(v) + 1.0f;
                if (ACT == 2) v = 0.5f * v * (1.0f + erff(v * 0.70710678118654752f));
                const size_t idx = row * (size_t)ldc + colE[nt];
                if (OBF16) {
                    Co16[idx] = f2b(v);
                } else {
                    if (ACCUM) v += Co32[idx];
                    if (RES)   v += b2f(res1[idx]) + res2[idx];
                    Co32[idx] = v;
                }
            }
        }
    }
}

// ---------------------------------------------------------------------------
__global__ __launch_bounds__(256)
void ln1024_bf16_kernel(const u16* __restrict__ in, u16* __restrict__ outp,
                        const float* __restrict__ g, const float* __restrict__ be) {
    const size_t base = (size_t)blockIdx.x * Dm;
    const int tid = threadIdx.x;
    ushort4 raw = *(const ushort4*)&in[base + tid * 4];
    float v0 = b2f(raw.x), v1 = b2f(raw.y), v2 = b2f(raw.z), v3 = b2f(raw.w);
    float s  = v0 + v1 + v2 + v3;
    float sq = v0 * v0 + v1 * v1 + v2 * v2 + v3 * v3;
    #pragma unroll
    for (int off = 32; off > 0; off >>= 1) {
        s  += __shfl_down(s,  off, 64);
        sq += __shfl_down(sq, off, 64);
    }
    __shared__ float rs[4], rq[4];
    const int lane = tid & 63, wv = tid >> 6;
    if (lane == 0) { rs[wv] = s; rq[wv] = sq; }
    __syncthreads();
    s  = rs[0] + rs[1] + rs[2] + rs[3];
    sq = rq[0] + rq[1] + rq[2] + rq[3];
    const float mean = s * (1.0f / 1024.0f);
    const float var  = sq * (1.0f / 1024.0f) - mean * mean;
    const float inv  = rsqrtf(var + 1e-5f);
    float4 gv = *(const float4*)&g[tid * 4];
    float4 bv = *(const float4*)&be[tid * 4];
    ushort4 o;
    o.x = f2b((v0 - mean) * inv * gv.x + bv.x);
    o.y = f2b((v1 - mean) * inv * gv.y + bv.y);
    o.z = f2b((v2 - mean) * inv * gv.z + bv.z);
    o.w = f2b((v3 - mean) * inv * gv.w + bv.w);
    *(ushort4*)&outp[base + tid * 4] = o;
}

__global__ __launch_bounds__(256)
void qprobe_kernel(const u16* __restrict__ Q, float* __restrict__ qp) {
    const int b = blockIdx.z;
    const int col = blockIdx.x * 256 + threadIdx.x;
    const int lchunk = Lq / 16;
    const int l0 = blockIdx.y * lchunk;
    const u16* p = Q + ((size_t)b * Lq + l0) * Dm + col;
    float s = 0.f;
    for (int l = 0; l < lchunk; ++l, p += Dm) s += b2f(*p);
    atomicAdd(&qp[b * Dm + col], s * (1.0f / (4096.0f * 8.0f)));
}

__global__ __launch_bounds__(256)
void logits_kernel(const u16* __restrict__ Kc, const float* __restrict__ qp,
                   float* __restrict__ score) {
    const int bh = blockIdx.y, b = bh >> 4, h = bh & 15;
    __shared__ float q[64];
    if (threadIdx.x < 64) q[threadIdx.x] = qp[b * Dm + h * 64 + threadIdx.x];
    __syncthreads();
    const int kr = blockIdx.x * 256 + threadIdx.x;
    const ushort4* krp = (const ushort4*)&Kc[((size_t)b * Lq + kr) * Dm + h * 64];
    float s = 0.f;
    #pragma unroll
    for (int i = 0; i < 16; ++i) {
        ushort4 v = krp[i];
        s += q[i * 4 + 0] * b2f(v.x) + q[i * 4 + 1] * b2f(v.y)
           + q[i * 4 + 2] * b2f(v.z) + q[i * 4 + 3] * b2f(v.w);
    }
    score[(size_t)bh * Lk1 + kr + 1] = s;
    if (blockIdx.x == 0 && threadIdx.x == 0) score[(size_t)bh * Lk1] = 0.f;
}

__global__ __launch_bounds__(256)
void softmax4097_kernel(float* __restrict__ sc) {
    __shared__ float buf[Lk1];
    __shared__ float red[8];
    const size_t base = (size_t)blockIdx.x * Lk1;
    const int tid = threadIdx.x;
    float mx = -1e30f;
    for (int i = tid; i < Lk1; i += 256) { float v = sc[base + i]; buf[i] = v; mx = fmaxf(mx, v); }
    #pragma unroll
    for (int off = 32; off > 0; off >>= 1) mx = fmaxf(mx, __shfl_down(mx, off, 64));
    const int lane = tid & 63, wv = tid >> 6;
    if (lane == 0) red[wv] = mx;
    __syncthreads();
    mx = fmaxf(fmaxf(red[0], red[1]), fmaxf(red[2], red[3]));
    float sum = 0.f;
    for (int i = tid; i < Lk1; i += 256) { float e = expf(buf[i] - mx); buf[i] = e; sum += e; }
    #pragma unroll
    for (int off = 32; off > 0; off >>= 1) sum += __shfl_down(sum, off, 64);
    if (lane == 0) red[4 + wv] = sum;
    __syncthreads();
    sum = red[4] + red[5] + red[6] + red[7];
    const float inv = 1.0f / sum;
    for (int i = tid; i < Lk1; i += 256) sc[base + i] = buf[i] * inv;
}

// ---------------------------------------------------------------------------
// KV[b,h,d,e] += sum_l (score[l+1]*phiK[l,d]) * V[l,e], fused Ksum
// ---------------------------------------------------------------------------
__global__ __launch_bounds__(256)
void kv_kernel(const u16* __restrict__ phiK, const u16* __restrict__ Vc,
               const float* __restrict__ sc, const float* __restrict__ bfk,
               float* __restrict__ KV, float* __restrict__ Ksum) {
    const int bh = blockIdx.y, b = bh >> 4, h = bh & 15;
    const int lchunk = Lq / 8;
    const int l0 = blockIdx.x * lchunk;
    __shared__ float pk[8][64];
    __shared__ float vv[8][64];
    __shared__ float red[8][64];
    const int i0 = (threadIdx.x >> 4) << 2;
    const int j0 = (threadIdx.x & 15) << 2;
    const int srr = threadIdx.x >> 5;
    const int scc = (threadIdx.x & 31) << 1;
    float acc[4][4] = {};
    float ks0 = 0.f, ks1 = 0.f;
    for (int lb = l0; lb < l0 + lchunk; lb += 8) {
        const float scv = sc[(size_t)bh * Lk1 + lb + srr + 1];
        const size_t off = ((size_t)b * Lq + lb + srr) * Dm + h * 64 + scc;
        ushort2 pv = *(const ushort2*)&phiK[off];
        ushort2 vb = *(const ushort2*)&Vc[off];
        const float p0 = b2f(pv.x) * scv, p1 = b2f(pv.y) * scv;
        pk[srr][scc]     = p0;
        pk[srr][scc + 1] = p1;
        vv[srr][scc]     = b2f(vb.x);
        vv[srr][scc + 1] = b2f(vb.y);
        ks0 += p0; ks1 += p1;
        __syncthreads();
        #pragma unroll
        for (int r = 0; r < 8; ++r) {
            float ra[4], rb[4];
            #pragma unroll
            for (int i = 0; i < 4; ++i) ra[i] = pk[r][i0 + i];
            #pragma unroll
            for (int j = 0; j < 4; ++j) rb[j] = vv[r][j0 + j];
            #pragma unroll
            for (int i = 0; i < 4; ++i)
                #pragma unroll
                for (int j = 0; j < 4; ++j)
                    acc[i][j] = fmaf(ra[i], rb[j], acc[i][j]);
        }
        __syncthreads();
    }
    red[srr][scc] = ks0;
    red[srr][scc + 1] = ks1;
    __syncthreads();
    if (threadIdx.x < 64) {
        float s = 0.f;
        #pragma unroll
        for (int r = 0; r < 8; ++r) s += red[r][threadIdx.x];
        if (blockIdx.x == 0)
            s += sc[(size_t)bh * Lk1] * (tanhf(bfk[h * 64 + threadIdx.x]) + 1.0f);
        atomicAdd(&Ksum[bh * 64 + threadIdx.x], s);
    }
    #pragma unroll
    for (int i = 0; i < 4; ++i)
        #pragma unroll
        for (int j = 0; j < 4; ++j)
            atomicAdd(&KV[((size_t)bh * 64 + i0 + i) * 64 + j0 + j], acc[i][j]);
}

// ---------------------------------------------------------------------------
// MFMA attnout (verified)
// ---------------------------------------------------------------------------
__global__ __launch_bounds__(256, 2)
void attnout_mfma_kernel(const u16* __restrict__ phiQ, const u16* __restrict__ KVT,
                         const float* __restrict__ Ksum, u16* __restrict__ outp) {
    __shared__ u16 pqs[256 * 64];
    __shared__ float kss[64];
    __shared__ float dns[256];
    const int bh = blockIdx.y, b = bh >> 4, h = bh & 15;
    const int l0 = blockIdx.x * 256;
    const int tid = threadIdx.x;
    const int l = tid & 63, w = tid >> 6;
    const int l16 = l & 15, l4 = l >> 4;

    bf16x8 bfr[4][2];
    {
        const u16* kb = KVT + (size_t)bh * 4096;
        #pragma unroll
        for (int n = 0; n < 4; ++n)
            #pragma unroll
            for (int kk = 0; kk < 2; ++kk)
                bfr[n][kk] = *(const bf16x8*)&kb[(n * 16 + l16) * 64 + kk * 32 + l4 * 8];
    }
    if (tid < 64) kss[tid] = Ksum[bh * 64 + tid];

    {
        const int rsub = tid >> 3;
        const int ssrc = ((tid & 7) ^ (rsub & 7)) * 8;
        u16* ldst = &pqs[(size_t)tid * 8];
        #pragma unroll
        for (int j = 0; j < 8; ++j) {
            const u16* g = phiQ + (((size_t)(b * Lq + l0 + j * 32 + rsub)) << 10)
                          + h * 64 + ssrc;
            GLL16(g, ldst + j * 2048);
        }
    }
    __syncthreads();

    {
        const int r7 = tid & 7;
        float s = 0.f;
        #pragma unroll
        for (int sl = 0; sl < 8; ++sl) {
            bf16x8 v = *(const bf16x8*)&pqs[tid * 64 + ((sl ^ r7) << 3)];
            #pragma unroll
            for (int j = 0; j < 8; ++j) s = fmaf(b2f(((u16*)&v)[j]), kss[sl * 8 + j], s);
        }
        dns[tid] = 1.0f / (s + 1e-6f);
    }

    f32x4 acc[4][4];
    const f32x4 zf = {0.f, 0.f, 0.f, 0.f};
    #pragma unroll
    for (int m = 0; m < 4; ++m)
        #pragma unroll
        for (int n = 0; n < 4; ++n) acc[m][n] = zf;
    #pragma unroll
    for (int kk = 0; kk < 2; ++kk) {
        bf16x8 afr[4];
        #pragma unroll
        for (int m = 0; m < 4; ++m) {
            const int row = w * 64 + m * 16 + l16;
            afr[m] = *(const bf16x8*)&pqs[row * 64 + (((kk * 4 + l4) ^ (row & 7)) << 3)];
        }
        #pragma unroll
        for (int m = 0; m < 4; ++m)
            #pragma unroll
            for (int n = 0; n < 4; ++n)
                acc[m][n] = __builtin_amdgcn_mfma_f32_16x16x32_bf16(
                    afr[m], bfr[n][kk], acc[m][n], 0, 0, 0);
    }
    __syncthreads();

    #pragma unroll
    for (int m = 0; m < 4; ++m) {
        #pragma unroll
        for (int q = 0; q < 4; ++q) {
            const int rl = w * 64 + m * 16 + l4 * 4 + q;
            const float dn = dns[rl];
            const size_t rowg = ((size_t)(b * Lq + l0 + rl)) << 10;
            #pragma unroll
            for (int n = 0; n < 4; ++n)
                outp[rowg + h * 64 + n * 16 + l16] = f2b(acc[m][n][q] * dn);
        }
    }
}

// ---------------------------------------------------------------------------
extern "C" void kernel_launch(void* const* d_in, const int* in_sizes, int n_in,
                              void* d_out, int out_size, void* d_ws, size_t ws_size,
                              hipStream_t stream) {
    const float* x     = (const float*)d_in[0];
    const float* Wq    = (const float*)d_in[1];
    const float* bq    = (const float*)d_in[2];
    const float* gq    = (const float*)d_in[3];
    const float* betaq = (const float*)d_in[4];
    const float* Wk    = (const float*)d_in[5];
    const float* bk    = (const float*)d_in[6];
    const float* gk    = (const float*)d_in[7];
    const float* betak = (const float*)d_in[8];
    const float* Wv    = (const float*)d_in[9];
    const float* bv    = (const float*)d_in[10];
    const float* gv    = (const float*)d_in[11];
    const float* betav = (const float*)d_in[12];
    const float* Wfq   = (const float*)d_in[13];
    const float* bfq   = (const float*)d_in[14];
    const float* Wfk   = (const float*)d_in[15];
    const float* bfk   = (const float*)d_in[16];
    const float* ga    = (const float*)d_in[17];
    const float* ba    = (const float*)d_in[18];
    const float* W1    = (const float*)d_in[19];
    const float* b1    = (const float*)d_in[20];
    const float* W2    = (const float*)d_in[21];
    const float* b2    = (const float*)d_in[22];
    float* outp = (float*)d_out;

    uint8_t* wsb = (uint8_t*)d_ws;
    size_t off = 0;
    auto alloc = [&](size_t bytes) { void* p = wsb + off; off += bytes; return p; };
    const size_t Md = (size_t)Mrows * Dm;
    u16* B0   = (u16*)alloc(Md * 2);
    u16* B1   = (u16*)alloc(Md * 2);
    u16* B2   = (u16*)alloc(Md * 2);
    u16* Wtq  = (u16*)alloc((size_t)Dm * Dm * 2);   // Wtq|Wtk contiguous
    u16* Wtk  = (u16*)alloc((size_t)Dm * Dm * 2);
    u16* Wtv  = (u16*)alloc((size_t)Dm * Dm * 2);
    u16* Wtfq = (u16*)alloc((size_t)Dm * Dm * 2);
    u16* Wtfk = (u16*)alloc((size_t)Dm * Dm * 2);
    u16* Wt1  = (u16*)alloc((size_t)Dm * Dmlp * 2);
    u16* Wt2  = (u16*)alloc((size_t)Dm * Dmlp * 2);
    float* qp    = (float*)alloc(4096 * 4);
    float* KV    = (float*)alloc((size_t)64 * 64 * 64 * 4);
    float* Ksum  = (float*)alloc(4096 * 4);
    float* score = (float*)alloc((size_t)64 * Lk1 * 4);
    u16* KVT     = (u16*)alloc((size_t)64 * 64 * 64 * 2);
    float* bqk   = (float*)alloc(2048 * 4);
    u16* PK = (u16*)outp;
    u16* PQ = (u16*)outp + Md;

    const dim3 blk(256);
    const dim3 blk512(512);
    const dim3 gA(256);
    const dim3 gQK(512);
    const dim3 gM(512);

    const int nz = 4096 + 64 * 64 * 64 + 4096;
    prep_kernel<<<6440, blk, 0, stream>>>(
        x, B0, Wq, Wk, Wv, Wfq, Wfk, W1, W2,
        Wtq, Wtk, Wtv, Wtfq, Wtfk, Wt1, Wt2,
        bq, bk, bqk, qp, nz);

    // 1) fused Q|K projection (N=2048, C-split lo->B1, hi->B2), then LNs
    mfma_gemm256<0, false, false, true, true><<<gQK, blk512, 0, stream>>>(
        B0, Dm, Wtq, Dm, bqk, B1, B2, 1024, 1024, nullptr, nullptr,
        Mrows, 2048, Dm);
    ln1024_bf16_kernel<<<Mrows, blk, 0, stream>>>(B1, B1, gq, betaq);
    ln1024_bf16_kernel<<<Mrows, blk, 0, stream>>>(B2, B2, gk, betak);

    // 2) probe softmax gating
    qprobe_kernel<<<dim3(Dm / 256, 16, Bc), blk, 0, stream>>>(B1, qp);
    logits_kernel<<<dim3(Lq / 256, 64), blk, 0, stream>>>(B2, qp, score);
    softmax4097_kernel<<<64, blk, 0, stream>>>(score);

    // 3) phiK -> PK ; phiQ -> PQ
    mfma_gemm256<1, false, false, true, true><<<gA, blk512, 0, stream>>>(
        B2, Dm, Wtfk, Dm, bfk, PK, PK, Dm, Dm, nullptr, nullptr,
        Mrows, Dm, Dm);
    mfma_gemm256<1, false, false, true, true><<<gA, blk512, 0, stream>>>(
        B1, Dm, Wtfq, Dm, bfq, PQ, PQ, Dm, Dm, nullptr, nullptr,
        Mrows, Dm, Dm);

    // 4) V = LN(x@Wv+bv) -> B1
    mfma_gemm256<0, false, false, true, true><<<gA, blk512, 0, stream>>>(
        B0, Dm, Wtv, Dm, bv, B1, B1, Dm, Dm, nullptr, nullptr,
        Mrows, Dm, Dm);
    ln1024_bf16_kernel<<<Mrows, blk, 0, stream>>>(B1, B1, gv, betav);

    // 5) KV (+fused Ksum), then KV -> KVT bf16
    kv_kernel<<<dim3(8, 64), blk, 0, stream>>>(PK, B1, score, bfk, KV, Ksum);
    kvt_cvt_kernel<<<64, blk, 0, stream>>>(KV, KVT);

    // 6) attention out (MFMA) -> B2, attn LN -> a (in B2)
    attnout_mfma_kernel<<<dim3(Lq / 256, 64), blk, 0, stream>>>(PQ, KVT, Ksum, B2);
    ln1024_bf16_kernel<<<Mrows, blk, 0, stream>>>(B2, B2, ga, ba);

    // 7) MLP, 2 chunks of 2048 hidden (H1 overlays B0+B1 contiguously)
    u16* H1 = B0;
    for (int c = 0; c < 2; ++c) {
        mfma_gemm256<2, false, false, true, true><<<gM, blk512, 0, stream>>>(
            B2, Dm, Wt1 + (size_t)c * 2048 * Dm, Dm, b1 + c * 2048,
            H1, H1, 2048, 2048, nullptr, nullptr, Mrows, 2048, Dm);
        if (c == 0) {
            mfma_gemm256<0, false, false, true, false><<<gA, blk512, 0, stream>>>(
                H1, 2048, Wt2 + (size_t)c * 2048, Dmlp, b2,
                outp, outp, Dm, Dm, nullptr, nullptr, Mrows, Dm, 2048);
        } else {
            mfma_gemm256<0, true, true, false, false><<<gA, blk512, 0, stream>>>(
                H1, 2048, Wt2 + (size_t)c * 2048, Dmlp, nullptr,
                outp, outp, Dm, Dm, B2, x, Mrows, Dm, 2048);
        }
    }
}

// Round 18
// 764.395 us; speedup vs baseline: 1.1221x; 1.1221x over previous
//
#include <hip/hip_runtime.h>
#include <cstddef>
#include <cstdint>

static constexpr int Bc   = 4;
static constexpr int Lq   = 4096;
static constexpr int Dm   = 1024;
static constexpr int Dmlp = 4096;
static constexpr int Mrows = Bc * Lq;   // 16384
static constexpr int Lk1   = Lq + 1;    // 4097

typedef unsigned short u16;
typedef __bf16 bf16_t;
typedef bf16_t bf16x8 __attribute__((ext_vector_type(8)));
typedef float  f32x4  __attribute__((ext_vector_type(4)));

__device__ __forceinline__ u16 f2b(float f) {
    uint32_t u = __builtin_bit_cast(uint32_t, f);
    return (u16)((u + 0x7FFFu + ((u >> 16) & 1u)) >> 16);
}
__device__ __forceinline__ float b2f(u16 h) {
    uint32_t u = ((uint32_t)h) << 16;
    return __builtin_bit_cast(float, u);
}

#define GLL16(gsrc, ldst) \
    __builtin_amdgcn_global_load_lds( \
        (const __attribute__((address_space(1))) void*)(gsrc), \
        (__attribute__((address_space(3))) void*)(ldst), 16, 0, 0)

// ---------------------------------------------------------------------------
// 64x64 transpose+convert tile (device helper)
// ---------------------------------------------------------------------------
__device__ __forceinline__
void transpose_tile(const float* __restrict__ in, u16* __restrict__ outp,
                    int R, int C, int tx, int ty) {
    __shared__ float tile[64][65];
    const int r0 = ty * 64, c0 = tx * 64;
    const int t = threadIdx.x;
    const int lr = t >> 2, lc0 = (t & 3) * 16;
    #pragma unroll
    for (int j = 0; j < 4; ++j) {
        float4 v = *(const float4*)&in[(size_t)(r0 + lr) * C + c0 + lc0 + j * 4];
        tile[lr][lc0 + j * 4 + 0] = v.x;
        tile[lr][lc0 + j * 4 + 1] = v.y;
        tile[lr][lc0 + j * 4 + 2] = v.z;
        tile[lr][lc0 + j * 4 + 3] = v.w;
    }
    __syncthreads();
    const int oc = t >> 2, rr0 = (t & 3) * 16;
    union { u16 u[16]; uint4 v[2]; } pk;
    #pragma unroll
    for (int j = 0; j < 16; ++j) pk.u[j] = f2b(tile[rr0 + j][oc]);
    u16* po = &outp[(size_t)(c0 + oc) * R + r0 + rr0];
    *(uint4*)&po[0] = pk.v[0];
    *(uint4*)&po[8] = pk.v[1];
}

// ---------------------------------------------------------------------------
// prep: cvt x->bf16 | 7 weight transposes | zero qp/KV/Ksum | bias concat
// ---------------------------------------------------------------------------
__global__ __launch_bounds__(256)
void prep_kernel(const float* __restrict__ x, u16* __restrict__ xb,
                 const float* __restrict__ Wq, const float* __restrict__ Wk,
                 const float* __restrict__ Wv, const float* __restrict__ Wfq,
                 const float* __restrict__ Wfk, const float* __restrict__ W1,
                 const float* __restrict__ W2,
                 u16* __restrict__ Wtq, u16* __restrict__ Wtk,
                 u16* __restrict__ Wtv, u16* __restrict__ Wtfq,
                 u16* __restrict__ Wtfk, u16* __restrict__ Wt1,
                 u16* __restrict__ Wt2,
                 const float* __restrict__ bq, const float* __restrict__ bk,
                 float* __restrict__ bqk,
                 float* __restrict__ zp, int nz) {
    int bid = blockIdx.x;
    if (bid < 2048) {
        const int n = Mrows * Dm;
        for (int i = (bid * 256 + threadIdx.x) * 4; i < n; i += 2048 * 256 * 4) {
            float4 v = *(const float4*)&x[i];
            ushort4 o = { f2b(v.x), f2b(v.y), f2b(v.z), f2b(v.w) };
            *(ushort4*)&xb[i] = o;
        }
        return;
    }
    bid -= 2048;
    if (bid < 3328) {
        const float* src; u16* dst; int R, C, tx, ty;
        if (bid < 1280) {
            const int wsel = bid >> 8, rem = bid & 255;
            if      (wsel == 0) { src = Wq;  dst = Wtq;  }
            else if (wsel == 1) { src = Wk;  dst = Wtk;  }
            else if (wsel == 2) { src = Wv;  dst = Wtv;  }
            else if (wsel == 3) { src = Wfq; dst = Wtfq; }
            else                { src = Wfk; dst = Wtfk; }
            R = 1024; C = 1024; tx = rem & 15; ty = rem >> 4;
        } else if (bid < 2304) {
            const int rem = bid - 1280;
            src = W1; dst = Wt1; R = 1024; C = 4096; tx = rem & 63; ty = rem >> 6;
        } else {
            const int rem = bid - 2304;
            src = W2; dst = Wt2; R = 4096; C = 1024; tx = rem & 15; ty = rem >> 4;
        }
        transpose_tile(src, dst, R, C, tx, ty);
        return;
    }
    bid -= 3328;
    if (bid < 1056) {
        const int i = bid * 256 + threadIdx.x;
        if (i < nz) zp[i] = 0.0f;
        return;
    }
    bid -= 1056;
    const int i = bid * 256 + threadIdx.x;
    bqk[i] = (i < 1024) ? bq[i] : bk[i - 1024];
}

// ---------------------------------------------------------------------------
// KVT[bh][e][d] = bf16(KV[bh][d][e])
// ---------------------------------------------------------------------------
__global__ __launch_bounds__(256)
void kvt_cvt_kernel(const float* __restrict__ KV, u16* __restrict__ KVT) {
    const int bh = blockIdx.x;
    __shared__ float t[64][65];
    const int tid = threadIdx.x;
    const int r = tid >> 2, c0 = (tid & 3) * 16;
    const float* src = &KV[(size_t)bh * 4096];
    #pragma unroll
    for (int j = 0; j < 4; ++j) {
        float4 v = *(const float4*)&src[r * 64 + c0 + j * 4];
        t[r][c0 + j * 4 + 0] = v.x;
        t[r][c0 + j * 4 + 1] = v.y;
        t[r][c0 + j * 4 + 2] = v.z;
        t[r][c0 + j * 4 + 3] = v.w;
    }
    __syncthreads();
    const int e = tid >> 2, d0 = (tid & 3) * 16;
    union { u16 u[16]; uint4 v[2]; } pk;
    #pragma unroll
    for (int j = 0; j < 16; ++j) pk.u[j] = f2b(t[d0 + j][e]);
    u16* po = &KVT[(size_t)bh * 4096 + e * 64 + d0];
    *(uint4*)&po[0] = pk.v[0];
    *(uint4*)&po[8] = pk.v[1];
}

// ---------------------------------------------------------------------------
// 256x256 MFMA GEMM, BK=32, ring-4 LDS (128 KiB), counted vmcnt, swizzles,
// setprio. 8 waves (2M x 4N), per-wave 128x64 out. (r6-verified inner loop,
// best-measured configuration: 767.6 us total.)
// Epilogue extension: optional N-split of bf16 output across Cout/Cout2 at
// nSplit with row stride ldc (degenerate nSplit=N, ldc=N elsewhere).
// ---------------------------------------------------------------------------
template<int ACT, bool RES, bool ACCUM, bool BIAS, bool OBF16>
__global__ __launch_bounds__(512, 1)
void mfma_gemm256(const u16* __restrict__ A, int ldA,
                  const u16* __restrict__ Bt, int ldB,
                  const float* __restrict__ bias,
                  void* __restrict__ Cout, void* __restrict__ Cout2,
                  int nSplit, int ldc,
                  const u16* __restrict__ res1, const float* __restrict__ res2,
                  int M, int N, int K) {
    __shared__ u16 ldsA[4][8192];
    __shared__ u16 ldsB[4][8192];
    const int tid = threadIdx.x;
    const int l   = tid & 63;
    const int w   = tid >> 6;
    const int wm  = w >> 2;
    const int wn  = w & 3;
    const int l16 = l & 15, l4 = l >> 4;

    const int gx = N >> 8;
    int bid = blockIdx.x;
    bid = (bid & 7) * ((int)gridDim.x >> 3) + (bid >> 3);
    const int brow = (bid / gx) << 8;
    const int bcol = (bid % gx) << 8;

    const int srow = w * 16 + (l >> 2);
    const int skof = ((l & 3) ^ ((l >> 3) & 3)) << 3;
    const u16* gA = A  + (size_t)(brow + srow) * ldA + skof;
    const u16* gB = Bt + (size_t)(bcol + srow) * ldB + skof;
    const size_t gsA = (size_t)128 * ldA;
    const size_t gsB = (size_t)128 * ldB;
    const int ldst = w * 512 + l * 8;

    const int koff_rd = ((l4 ^ ((l16 >> 1) & 3)) << 3);
    const int aRdBase = (wm * 128 + l16) * 32 + koff_rd;
    const int bRdBase = (wn * 64  + l16) * 32 + koff_rd;

    f32x4 acc[8][4];
    const f32x4 zf = {0.f, 0.f, 0.f, 0.f};
    #pragma unroll
    for (int m = 0; m < 8; ++m)
        #pragma unroll
        for (int n = 0; n < 4; ++n) acc[m][n] = zf;

    auto stageA = [&](int slot, int kelem) {
        const u16* s = gA + (size_t)kelem;
        GLL16(s,       &ldsA[slot][ldst]);
        GLL16(s + gsA, &ldsA[slot][ldst + 4096]);
    };
    auto stageB = [&](int slot, int kelem) {
        const u16* s = gB + (size_t)kelem;
        GLL16(s,       &ldsB[slot][ldst]);
        GLL16(s + gsB, &ldsB[slot][ldst + 4096]);
    };

    const int T = K >> 5;
    stageA(0, 0);  stageB(0, 0);
    stageA(1, 32); stageB(1, 32);
    stageA(2, 64); stageB(2, 64);

    auto step = [&](int t, int waitsel, bool do_stage) {
        asm volatile("s_waitcnt lgkmcnt(0)" ::: "memory");
        if (waitsel == 0)      asm volatile("s_waitcnt vmcnt(8)" ::: "memory");
        else if (waitsel == 1) asm volatile("s_waitcnt vmcnt(4)" ::: "memory");
        else                   asm volatile("s_waitcnt vmcnt(0)" ::: "memory");
        asm volatile("s_barrier" ::: "memory");
        const int slot = t & 3;
        bf16x8 afr[4], bfr[4];
        #pragma unroll
        for (int n = 0; n < 4; ++n)
            bfr[n] = *(const bf16x8*)&ldsB[slot][bRdBase + n * 512];
        #pragma unroll
        for (int m = 0; m < 4; ++m)
            afr[m] = *(const bf16x8*)&ldsA[slot][aRdBase + m * 512];
        if (do_stage) stageA((t + 3) & 3, (t + 3) * 32);
        __builtin_amdgcn_s_setprio(1);
        #pragma unroll
        for (int m = 0; m < 4; ++m)
            #pragma unroll
            for (int n = 0; n < 4; ++n)
                acc[m][n] = __builtin_amdgcn_mfma_f32_16x16x32_bf16(
                    afr[m], bfr[n], acc[m][n], 0, 0, 0);
        __builtin_amdgcn_s_setprio(0);
        #pragma unroll
        for (int m = 0; m < 4; ++m)
            afr[m] = *(const bf16x8*)&ldsA[slot][aRdBase + (m + 4) * 512];
        if (do_stage) stageB((t + 3) & 3, (t + 3) * 32);
        __builtin_amdgcn_s_setprio(1);
        #pragma unroll
        for (int m = 0; m < 4; ++m)
            #pragma unroll
            for (int n = 0; n < 4; ++n)
                acc[m + 4][n] = __builtin_amdgcn_mfma_f32_16x16x32_bf16(
                    afr[m], bfr[n], acc[m + 4][n], 0, 0, 0);
        __builtin_amdgcn_s_setprio(0);
    };

    for (int t = 0; t < T - 2; ++t) step(t, 0, (t + 3) < T);
    step(T - 2, 1, false);
    step(T - 1, 2, false);

    // --- epilogue (optional bf16 N-split) ---
    const bool hiC = (bcol >= nSplit);
    u16*   Co16 = (u16*)(hiC ? Cout2 : Cout);
    float* Co32 = (float*)Cout;
    const int bcolE = bcol - (hiC ? nSplit : 0);
    float bvn[4];
    int colE[4];
    #pragma unroll
    for (int n = 0; n < 4; ++n) {
        const int cg = bcol + wn * 64 + n * 16 + l16;
        colE[n] = bcolE + wn * 64 + n * 16 + l16;
        bvn[n] = BIAS ? bias[cg] : 0.f;
    }
    #pragma unroll
    for (int m = 0; m < 8; ++m) {
        #pragma unroll
        for (int q = 0; q < 4; ++q) {
            const size_t row = (size_t)brow + wm * 128 + m * 16 + l4 * 4 + q;
            #pragma unroll
            for (int n = 0; n < 4; ++n) {
                float v = acc[m][n][q] + bvn[n];
                if (ACT == 1) v = tanhf(v) + 1.0f;
                if (ACT == 2) v = 0.5f * v * (1.0f + erff(v * 0.70710678118654752f));
                const size_t idx = row * (size_t)ldc + colE[n];
                if (OBF16) {
                    Co16[idx] = f2b(v);
                } else {
                    if (ACCUM) v += Co32[idx];
                    if (RES)   v += b2f(res1[idx]) + res2[idx];
                    Co32[idx] = v;
                }
            }
        }
    }
}

// ---------------------------------------------------------------------------
__global__ __launch_bounds__(256)
void ln1024_bf16_kernel(const u16* __restrict__ in, u16* __restrict__ outp,
                        const float* __restrict__ g, const float* __restrict__ be) {
    const size_t base = (size_t)blockIdx.x * Dm;
    const int tid = threadIdx.x;
    ushort4 raw = *(const ushort4*)&in[base + tid * 4];
    float v0 = b2f(raw.x), v1 = b2f(raw.y), v2 = b2f(raw.z), v3 = b2f(raw.w);
    float s  = v0 + v1 + v2 + v3;
    float sq = v0 * v0 + v1 * v1 + v2 * v2 + v3 * v3;
    #pragma unroll
    for (int off = 32; off > 0; off >>= 1) {
        s  += __shfl_down(s,  off, 64);
        sq += __shfl_down(sq, off, 64);
    }
    __shared__ float rs[4], rq[4];
    const int lane = tid & 63, wv = tid >> 6;
    if (lane == 0) { rs[wv] = s; rq[wv] = sq; }
    __syncthreads();
    s  = rs[0] + rs[1] + rs[2] + rs[3];
    sq = rq[0] + rq[1] + rq[2] + rq[3];
    const float mean = s * (1.0f / 1024.0f);
    const float var  = sq * (1.0f / 1024.0f) - mean * mean;
    const float inv  = rsqrtf(var + 1e-5f);
    float4 gv = *(const float4*)&g[tid * 4];
    float4 bv = *(const float4*)&be[tid * 4];
    ushort4 o;
    o.x = f2b((v0 - mean) * inv * gv.x + bv.x);
    o.y = f2b((v1 - mean) * inv * gv.y + bv.y);
    o.z = f2b((v2 - mean) * inv * gv.z + bv.z);
    o.w = f2b((v3 - mean) * inv * gv.w + bv.w);
    *(ushort4*)&outp[base + tid * 4] = o;
}

__global__ __launch_bounds__(256)
void qprobe_kernel(const u16* __restrict__ Q, float* __restrict__ qp) {
    const int b = blockIdx.z;
    const int col = blockIdx.x * 256 + threadIdx.x;
    const int lchunk = Lq / 16;
    const int l0 = blockIdx.y * lchunk;
    const u16* p = Q + ((size_t)b * Lq + l0) * Dm + col;
    float s = 0.f;
    for (int l = 0; l < lchunk; ++l, p += Dm) s += b2f(*p);
    atomicAdd(&qp[b * Dm + col], s * (1.0f / (4096.0f * 8.0f)));
}

__global__ __launch_bounds__(256)
void logits_kernel(const u16* __restrict__ Kc, const float* __restrict__ qp,
                   float* __restrict__ score) {
    const int bh = blockIdx.y, b = bh >> 4, h = bh & 15;
    __shared__ float q[64];
    if (threadIdx.x < 64) q[threadIdx.x] = qp[b * Dm + h * 64 + threadIdx.x];
    __syncthreads();
    const int kr = blockIdx.x * 256 + threadIdx.x;
    const ushort4* krp = (const ushort4*)&Kc[((size_t)b * Lq + kr) * Dm + h * 64];
    float s = 0.f;
    #pragma unroll
    for (int i = 0; i < 16; ++i) {
        ushort4 v = krp[i];
        s += q[i * 4 + 0] * b2f(v.x) + q[i * 4 + 1] * b2f(v.y)
           + q[i * 4 + 2] * b2f(v.z) + q[i * 4 + 3] * b2f(v.w);
    }
    score[(size_t)bh * Lk1 + kr + 1] = s;
    if (blockIdx.x == 0 && threadIdx.x == 0) score[(size_t)bh * Lk1] = 0.f;
}

__global__ __launch_bounds__(256)
void softmax4097_kernel(float* __restrict__ sc) {
    __shared__ float buf[Lk1];
    __shared__ float red[8];
    const size_t base = (size_t)blockIdx.x * Lk1;
    const int tid = threadIdx.x;
    float mx = -1e30f;
    for (int i = tid; i < Lk1; i += 256) { float v = sc[base + i]; buf[i] = v; mx = fmaxf(mx, v); }
    #pragma unroll
    for (int off = 32; off > 0; off >>= 1) mx = fmaxf(mx, __shfl_down(mx, off, 64));
    const int lane = tid & 63, wv = tid >> 6;
    if (lane == 0) red[wv] = mx;
    __syncthreads();
    mx = fmaxf(fmaxf(red[0], red[1]), fmaxf(red[2], red[3]));
    float sum = 0.f;
    for (int i = tid; i < Lk1; i += 256) { float e = expf(buf[i] - mx); buf[i] = e; sum += e; }
    #pragma unroll
    for (int off = 32; off > 0; off >>= 1) sum += __shfl_down(sum, off, 64);
    if (lane == 0) red[4 + wv] = sum;
    __syncthreads();
    sum = red[4] + red[5] + red[6] + red[7];
    const float inv = 1.0f / sum;
    for (int i = tid; i < Lk1; i += 256) sc[base + i] = buf[i] * inv;
}

// ---------------------------------------------------------------------------
// KV[b,h,d,e] += sum_l (score[l+1]*phiK[l,d]) * V[l,e], fused Ksum
// (column-sum of the staged pk tiles + zero-token term in block 0).
// ---------------------------------------------------------------------------
__global__ __launch_bounds__(256)
void kv_kernel(const u16* __restrict__ phiK, const u16* __restrict__ Vc,
               const float* __restrict__ sc, const float* __restrict__ bfk,
               float* __restrict__ KV, float* __restrict__ Ksum) {
    const int bh = blockIdx.y, b = bh >> 4, h = bh & 15;
    const int lchunk = Lq / 8;
    const int l0 = blockIdx.x * lchunk;
    __shared__ float pk[8][64];
    __shared__ float vv[8][64];
    __shared__ float red[8][64];
    const int i0 = (threadIdx.x >> 4) << 2;
    const int j0 = (threadIdx.x & 15) << 2;
    const int srr = threadIdx.x >> 5;          // staging row 0..7
    const int scc = (threadIdx.x & 31) << 1;   // staging col 0,2,..,62
    float acc[4][4] = {};
    float ks0 = 0.f, ks1 = 0.f;
    for (int lb = l0; lb < l0 + lchunk; lb += 8) {
        const float scv = sc[(size_t)bh * Lk1 + lb + srr + 1];
        const size_t off = ((size_t)b * Lq + lb + srr) * Dm + h * 64 + scc;
        ushort2 pv = *(const ushort2*)&phiK[off];
        ushort2 vb = *(const ushort2*)&Vc[off];
        const float p0 = b2f(pv.x) * scv, p1 = b2f(pv.y) * scv;
        pk[srr][scc]     = p0;
        pk[srr][scc + 1] = p1;
        vv[srr][scc]     = b2f(vb.x);
        vv[srr][scc + 1] = b2f(vb.y);
        ks0 += p0; ks1 += p1;
        __syncthreads();
        #pragma unroll
        for (int r = 0; r < 8; ++r) {
            float ra[4], rb[4];
            #pragma unroll
            for (int i = 0; i < 4; ++i) ra[i] = pk[r][i0 + i];
            #pragma unroll
            for (int j = 0; j < 4; ++j) rb[j] = vv[r][j0 + j];
            #pragma unroll
            for (int i = 0; i < 4; ++i)
                #pragma unroll
                for (int j = 0; j < 4; ++j)
                    acc[i][j] = fmaf(ra[i], rb[j], acc[i][j]);
        }
        __syncthreads();
    }
    // Ksum: reduce per-column partials across the 8 staging rows
    red[srr][scc] = ks0;
    red[srr][scc + 1] = ks1;
    __syncthreads();
    if (threadIdx.x < 64) {
        float s = 0.f;
        #pragma unroll
        for (int r = 0; r < 8; ++r) s += red[r][threadIdx.x];
        if (blockIdx.x == 0)
            s += sc[(size_t)bh * Lk1] * (tanhf(bfk[h * 64 + threadIdx.x]) + 1.0f);
        atomicAdd(&Ksum[bh * 64 + threadIdx.x], s);
    }
    #pragma unroll
    for (int i = 0; i < 4; ++i)
        #pragma unroll
        for (int j = 0; j < 4; ++j)
            atomicAdd(&KV[((size_t)bh * 64 + i0 + i) * 64 + j0 + j], acc[i][j]);
}

// ---------------------------------------------------------------------------
// MFMA attnout (verified)
// ---------------------------------------------------------------------------
__global__ __launch_bounds__(256, 2)
void attnout_mfma_kernel(const u16* __restrict__ phiQ, const u16* __restrict__ KVT,
                         const float* __restrict__ Ksum, u16* __restrict__ outp) {
    __shared__ u16 pqs[256 * 64];
    __shared__ float kss[64];
    __shared__ float dns[256];
    const int bh = blockIdx.y, b = bh >> 4, h = bh & 15;
    const int l0 = blockIdx.x * 256;
    const int tid = threadIdx.x;
    const int l = tid & 63, w = tid >> 6;
    const int l16 = l & 15, l4 = l >> 4;

    bf16x8 bfr[4][2];
    {
        const u16* kb = KVT + (size_t)bh * 4096;
        #pragma unroll
        for (int n = 0; n < 4; ++n)
            #pragma unroll
            for (int kk = 0; kk < 2; ++kk)
                bfr[n][kk] = *(const bf16x8*)&kb[(n * 16 + l16) * 64 + kk * 32 + l4 * 8];
    }
    if (tid < 64) kss[tid] = Ksum[bh * 64 + tid];

    {
        const int rsub = tid >> 3;
        const int ssrc = ((tid & 7) ^ (rsub & 7)) * 8;
        u16* ldst = &pqs[(size_t)tid * 8];
        #pragma unroll
        for (int j = 0; j < 8; ++j) {
            const u16* g = phiQ + (((size_t)(b * Lq + l0 + j * 32 + rsub)) << 10)
                          + h * 64 + ssrc;
            GLL16(g, ldst + j * 2048);
        }
    }
    __syncthreads();

    {
        const int r7 = tid & 7;
        float s = 0.f;
        #pragma unroll
        for (int sl = 0; sl < 8; ++sl) {
            bf16x8 v = *(const bf16x8*)&pqs[tid * 64 + ((sl ^ r7) << 3)];
            #pragma unroll
            for (int j = 0; j < 8; ++j) s = fmaf(b2f(((u16*)&v)[j]), kss[sl * 8 + j], s);
        }
        dns[tid] = 1.0f / (s + 1e-6f);
    }

    f32x4 acc[4][4];
    const f32x4 zf = {0.f, 0.f, 0.f, 0.f};
    #pragma unroll
    for (int m = 0; m < 4; ++m)
        #pragma unroll
        for (int n = 0; n < 4; ++n) acc[m][n] = zf;
    #pragma unroll
    for (int kk = 0; kk < 2; ++kk) {
        bf16x8 afr[4];
        #pragma unroll
        for (int m = 0; m < 4; ++m) {
            const int row = w * 64 + m * 16 + l16;
            afr[m] = *(const bf16x8*)&pqs[row * 64 + (((kk * 4 + l4) ^ (row & 7)) << 3)];
        }
        #pragma unroll
        for (int m = 0; m < 4; ++m)
            #pragma unroll
            for (int n = 0; n < 4; ++n)
                acc[m][n] = __builtin_amdgcn_mfma_f32_16x16x32_bf16(
                    afr[m], bfr[n][kk], acc[m][n], 0, 0, 0);
    }
    __syncthreads();

    #pragma unroll
    for (int m = 0; m < 4; ++m) {
        #pragma unroll
        for (int q = 0; q < 4; ++q) {
            const int rl = w * 64 + m * 16 + l4 * 4 + q;
            const float dn = dns[rl];
            const size_t rowg = ((size_t)(b * Lq + l0 + rl)) << 10;
            #pragma unroll
            for (int n = 0; n < 4; ++n)
                outp[rowg + h * 64 + n * 16 + l16] = f2b(acc[m][n][q] * dn);
        }
    }
}

// ---------------------------------------------------------------------------
extern "C" void kernel_launch(void* const* d_in, const int* in_sizes, int n_in,
                              void* d_out, int out_size, void* d_ws, size_t ws_size,
                              hipStream_t stream) {
    const float* x     = (const float*)d_in[0];
    const float* Wq    = (const float*)d_in[1];
    const float* bq    = (const float*)d_in[2];
    const float* gq    = (const float*)d_in[3];
    const float* betaq = (const float*)d_in[4];
    const float* Wk    = (const float*)d_in[5];
    const float* bk    = (const float*)d_in[6];
    const float* gk    = (const float*)d_in[7];
    const float* betak = (const float*)d_in[8];
    const float* Wv    = (const float*)d_in[9];
    const float* bv    = (const float*)d_in[10];
    const float* gv    = (const float*)d_in[11];
    const float* betav = (const float*)d_in[12];
    const float* Wfq   = (const float*)d_in[13];
    const float* bfq   = (const float*)d_in[14];
    const float* Wfk   = (const float*)d_in[15];
    const float* bfk   = (const float*)d_in[16];
    const float* ga    = (const float*)d_in[17];
    const float* ba    = (const float*)d_in[18];
    const float* W1    = (const float*)d_in[19];
    const float* b1    = (const float*)d_in[20];
    const float* W2    = (const float*)d_in[21];
    const float* b2    = (const float*)d_in[22];
    float* outp = (float*)d_out;

    uint8_t* wsb = (uint8_t*)d_ws;
    size_t off = 0;
    auto alloc = [&](size_t bytes) { void* p = wsb + off; off += bytes; return p; };
    const size_t Md = (size_t)Mrows * Dm;
    u16* B0   = (u16*)alloc(Md * 2);
    u16* B1   = (u16*)alloc(Md * 2);
    u16* B2   = (u16*)alloc(Md * 2);
    u16* Wtq  = (u16*)alloc((size_t)Dm * Dm * 2);   // Wtq|Wtk contiguous
    u16* Wtk  = (u16*)alloc((size_t)Dm * Dm * 2);
    u16* Wtv  = (u16*)alloc((size_t)Dm * Dm * 2);
    u16* Wtfq = (u16*)alloc((size_t)Dm * Dm * 2);
    u16* Wtfk = (u16*)alloc((size_t)Dm * Dm * 2);
    u16* Wt1  = (u16*)alloc((size_t)Dm * Dmlp * 2);
    u16* Wt2  = (u16*)alloc((size_t)Dm * Dmlp * 2);
    float* qp    = (float*)alloc(4096 * 4);
    float* KV    = (float*)alloc((size_t)64 * 64 * 64 * 4);
    float* Ksum  = (float*)alloc(4096 * 4);
    float* score = (float*)alloc((size_t)64 * Lk1 * 4);
    u16* KVT     = (u16*)alloc((size_t)64 * 64 * 64 * 2);
    float* bqk   = (float*)alloc(2048 * 4);
    u16* PK = (u16*)outp;
    u16* PQ = (u16*)outp + Md;

    const dim3 blk(256);
    const dim3 blk512(512);
    const dim3 gA(256);    // N=1024 grids
    const dim3 gQK(512);   // fused QK, N=2048
    const dim3 gM(512);    // MLP1 chunks, N=2048

    // 0) fused prep: cvt + 7 transposes + zero + bias concat
    const int nz = 4096 + 64 * 64 * 64 + 4096;
    prep_kernel<<<6440, blk, 0, stream>>>(
        x, B0, Wq, Wk, Wv, Wfq, Wfk, W1, W2,
        Wtq, Wtk, Wtv, Wtfq, Wtfk, Wt1, Wt2,
        bq, bk, bqk, qp, nz);

    // 1) fused Q|K projection (N=2048, C-split lo->B1, hi->B2), then LNs
    mfma_gemm256<0, false, false, true, true><<<gQK, blk512, 0, stream>>>(
        B0, Dm, Wtq, Dm, bqk, B1, B2, 1024, 1024, nullptr, nullptr,
        Mrows, 2048, Dm);
    ln1024_bf16_kernel<<<Mrows, blk, 0, stream>>>(B1, B1, gq, betaq);
    ln1024_bf16_kernel<<<Mrows, blk, 0, stream>>>(B2, B2, gk, betak);

    // 2) probe softmax gating
    qprobe_kernel<<<dim3(Dm / 256, 16, Bc), blk, 0, stream>>>(B1, qp);
    logits_kernel<<<dim3(Lq / 256, 64), blk, 0, stream>>>(B2, qp, score);
    softmax4097_kernel<<<64, blk, 0, stream>>>(score);

    // 3) phiK -> PK ; phiQ -> PQ
    mfma_gemm256<1, false, false, true, true><<<gA, blk512, 0, stream>>>(
        B2, Dm, Wtfk, Dm, bfk, PK, PK, Dm, Dm, nullptr, nullptr,
        Mrows, Dm, Dm);
    mfma_gemm256<1, false, false, true, true><<<gA, blk512, 0, stream>>>(
        B1, Dm, Wtfq, Dm, bfq, PQ, PQ, Dm, Dm, nullptr, nullptr,
        Mrows, Dm, Dm);

    // 4) V = LN(x@Wv+bv) -> B1  (Q_ln dead after phiQ)
    mfma_gemm256<0, false, false, true, true><<<gA, blk512, 0, stream>>>(
        B0, Dm, Wtv, Dm, bv, B1, B1, Dm, Dm, nullptr, nullptr,
        Mrows, Dm, Dm);
    ln1024_bf16_kernel<<<Mrows, blk, 0, stream>>>(B1, B1, gv, betav);

    // 5) KV (+fused Ksum), then KV -> KVT bf16
    kv_kernel<<<dim3(8, 64), blk, 0, stream>>>(PK, B1, score, bfk, KV, Ksum);
    kvt_cvt_kernel<<<64, blk, 0, stream>>>(KV, KVT);

    // 6) attention out (MFMA) -> B2, attn LN -> a (in B2)
    attnout_mfma_kernel<<<dim3(Lq / 256, 64), blk, 0, stream>>>(PQ, KVT, Ksum, B2);
    ln1024_bf16_kernel<<<Mrows, blk, 0, stream>>>(B2, B2, ga, ba);

    // 7) MLP, 2 chunks of 2048 hidden (H1 overlays B0+B1 contiguously)
    u16* H1 = B0;
    for (int c = 0; c < 2; ++c) {
        mfma_gemm256<2, false, false, true, true><<<gM, blk512, 0, stream>>>(
            B2, Dm, Wt1 + (size_t)c * 2048 * Dm, Dm, b1 + c * 2048,
            H1, H1, 2048, 2048, nullptr, nullptr, Mrows, 2048, Dm);
        if (c == 0) {
            mfma_gemm256<0, false, false, true, false><<<gA, blk512, 0, stream>>>(
                H1, 2048, Wt2 + (size_t)c * 2048, Dmlp, b2,
                outp, outp, Dm, Dm, nullptr, nullptr, Mrows, Dm, 2048);
        } else {
            mfma_gemm256<0, true, true, false, false><<<gA, blk512, 0, stream>>>(
                H1, 2048, Wt2 + (size_t)c * 2048, Dmlp, nullptr,
                outp, outp, Dm, Dm, B2, x, Mrows, Dm, 2048);
        }
    }
}